// Round 1
// baseline (12102.259 us; speedup 1.0000x reference)
//
#include <hip/hip_runtime.h>
#include <cstdint>
#include <cstddef>

// ConvVFE: voxelize -> per-voxel mean -> MLP(10->32)+BN+ReLU -> voxel max
// -> concat -> MLP(64->128)+BN+ReLU -> voxel max ; plus voxel coords.
//
// merge id = b*55000 + cx*250 + cy (+cz, cz==0), bounded by 220000 ->
// dense histogram + ordered prefix scan reproduces jnp.unique sorted order.

constexpr int M_IDS  = 220000;            // 4 * 220 * 250 * 1
constexpr int CH     = 256;               // scan chunk
constexpr int NCHUNK = (M_IDS + CH - 1) / CH;   // 860

// ---------------------------------------------------------------- K1: histogram
__global__ void k1_count(const float* __restrict__ pts, int* __restrict__ inv,
                         int* __restrict__ cnt, float* __restrict__ sums, int N)
{
    int i = blockIdx.x * blockDim.x + threadIdx.x;
    if (i >= N) return;
    const float* p = pts + (size_t)i * 5;
    float b = p[0], x = p[1], y = p[2], z = p[3];
    // IEEE fp32 division to bit-match numpy's floor((p - pcr)/vsz)
    float fx = floorf((x - 0.0f) / 0.32f);
    float fy = floorf((y + 40.0f) / 0.32f);
    float fz = floorf((z + 3.0f) / 4.0f);
    bool ok = (fx >= 0.0f) && (fx < 220.0f) && (fy >= 0.0f) && (fy < 250.0f) &&
              (fz >= 0.0f) && (fz < 1.0f);
    if (!ok) { inv[i] = -1; return; }
    int merge = (int)b * 55000 + (int)fx * 250 + (int)fy + (int)fz;
    inv[i] = merge;
    atomicAdd(&cnt[merge], 1);
    atomicAdd(&sums[merge * 3 + 0], x);
    atomicAdd(&sums[merge * 3 + 1], y);
    atomicAdd(&sums[merge * 3 + 2], z);
}

// ---------------------------------------------------------------- K2: ordered compaction
__global__ void k2a_chunktot(const int* __restrict__ cnt, int* __restrict__ chunkTot,
                             int* __restrict__ np)
{
    __shared__ int so[CH], sc[CH];
    int tid = threadIdx.x;
    int id = blockIdx.x * CH + tid;
    int c = (id < M_IDS) ? cnt[id] : 0;
    so[tid] = (c > 0) ? 1 : 0;
    sc[tid] = c;
    __syncthreads();
    for (int s = CH / 2; s > 0; s >>= 1) {
        if (tid < s) { so[tid] += so[tid + s]; sc[tid] += sc[tid + s]; }
        __syncthreads();
    }
    if (tid == 0) { chunkTot[blockIdx.x] = so[0]; atomicAdd(np, sc[0]); }
}

__global__ void k2b_scan(const int* __restrict__ chunkTot, int* __restrict__ chunkBase)
{
    __shared__ int ls[1024];
    int t = threadIdx.x;
    int v = (t < NCHUNK) ? chunkTot[t] : 0;
    ls[t] = v;
    __syncthreads();
    for (int off = 1; off < 1024; off <<= 1) {
        int x = (t >= off) ? ls[t - off] : 0;
        __syncthreads();
        ls[t] += x;
        __syncthreads();
    }
    chunkBase[t] = ls[t] - v;   // exclusive
}

__global__ void k2c_index(const int* __restrict__ cnt, const float* __restrict__ sums,
                          const int* __restrict__ chunkBase, int* __restrict__ idxArr,
                          float* __restrict__ meanArr, float* __restrict__ outCoords)
{
    __shared__ int ls[CH];
    int tid = threadIdx.x;
    int id = blockIdx.x * CH + tid;
    int c = (id < M_IDS) ? cnt[id] : 0;
    int occ = (c > 0) ? 1 : 0;
    ls[tid] = occ;
    __syncthreads();
    for (int off = 1; off < CH; off <<= 1) {
        int x = (tid >= off) ? ls[tid - off] : 0;
        __syncthreads();
        ls[tid] += x;
        __syncthreads();
    }
    int g = chunkBase[blockIdx.x] + ls[tid] - occ;
    if (id < M_IDS) idxArr[id] = g;
    if (occ) {
        float fc = (float)c;
        meanArr[(size_t)g * 3 + 0] = sums[(size_t)id * 3 + 0] / fc;
        meanArr[(size_t)g * 3 + 1] = sums[(size_t)id * 3 + 1] / fc;
        meanArr[(size_t)g * 3 + 2] = sums[(size_t)id * 3 + 2] / fc;
        int b  = id / 55000;
        int rm = id % 55000;
        int cx = rm / 250;
        int cy = rm % 250;
        outCoords[(size_t)g * 4 + 0] = (float)b;
        outCoords[(size_t)g * 4 + 1] = 0.0f;
        outCoords[(size_t)g * 4 + 2] = (float)cy;
        outCoords[(size_t)g * 4 + 3] = (float)cx;
    }
}

// ---------------------------------------------------------------- feats -> y0 (10x32)
__device__ __forceinline__ void feats_y0(const float* __restrict__ pts, int i,
                                         const float* __restrict__ meanArr, int v,
                                         const float* __restrict__ w0, float y0[32])
{
    const float* p = pts + (size_t)i * 5;
    float x = p[1], y = p[2], z = p[3], it = p[4];
    float fx = floorf((x - 0.0f) / 0.32f);
    float fy = floorf((y + 40.0f) / 0.32f);
    float f[10];
    f[0] = x; f[1] = y; f[2] = z; f[3] = it;
    f[4] = x - meanArr[(size_t)v * 3 + 0];
    f[5] = y - meanArr[(size_t)v * 3 + 1];
    f[6] = z - meanArr[(size_t)v * 3 + 2];
    f[7] = x - (fx * 0.32f + 0.16f);
    f[8] = y - (fy * 0.32f + (-39.84f));
    f[9] = z + 1.0f;                        // z - Z_OFF, Z_OFF = -1.0
#pragma unroll
    for (int c = 0; c < 32; c++) y0[c] = 0.0f;
#pragma unroll
    for (int d = 0; d < 10; d++) {
        float fd = f[d];
#pragma unroll
        for (int c = 0; c < 32; c++) y0[c] += fd * w0[d * 32 + c];   // w0 uniform -> s_load
    }
}

// ---------------------------------------------------------------- K3: BN0 stats (+inv compaction)
__global__ void k3_stats0(const float* __restrict__ pts, const float* __restrict__ w0,
                          const int* __restrict__ idxArr, int* __restrict__ inv,
                          const float* __restrict__ meanArr, float* __restrict__ stats0,
                          int N)
{
    float rs[32], rq[32];
#pragma unroll
    for (int c = 0; c < 32; c++) { rs[c] = 0.0f; rq[c] = 0.0f; }
    int gid = blockIdx.x * blockDim.x + threadIdx.x;
    int gsz = gridDim.x * blockDim.x;
    for (int i = gid; i < N; i += gsz) {
        int m = inv[i];
        int v = (m >= 0) ? idxArr[m] : -1;
        inv[i] = v;
        if (v < 0) continue;
        float y0[32];
        feats_y0(pts, i, meanArr, v, w0, y0);
#pragma unroll
        for (int c = 0; c < 32; c++) { rs[c] += y0[c]; rq[c] += y0[c] * y0[c]; }
    }
    // wave allreduce after loop (all lanes converged here)
    int lane = threadIdx.x & 63;
#pragma unroll
    for (int c = 0; c < 32; c++) {
        float s = rs[c], q = rq[c];
#pragma unroll
        for (int msk = 1; msk < 64; msk <<= 1) {
            s += __shfl_xor(s, msk);
            q += __shfl_xor(q, msk);
        }
        if (lane == c)      atomicAdd(&stats0[c], s);
        if (lane == 32 + c) atomicAdd(&stats0[32 + c], q);
    }
}

// ---------------------------------------------------------------- BN finalize (scale/bias)
__global__ void k_bnfin(const float* __restrict__ stats, const int* __restrict__ np,
                        const float* __restrict__ g, const float* __restrict__ b,
                        float* __restrict__ sb, int C)
{
    int c = blockIdx.x * blockDim.x + threadIdx.x;
    if (c >= C) return;
    float n   = (float)(*np);
    float mu  = stats[c] / n;
    float var = stats[C + c] / n - mu * mu;
    float s   = g[c] / sqrtf(var + 1e-3f);
    sb[c]     = s;
    sb[C + c] = b[c] - mu * s;
}

// ---------------------------------------------------------------- K5: x0 voxel max
__global__ void k5_xmax(const float* __restrict__ pts, const float* __restrict__ w0,
                        const int* __restrict__ inv, const float* __restrict__ meanArr,
                        const float* __restrict__ sb0, unsigned int* __restrict__ xmax,
                        int N)
{
    int i = blockIdx.x * blockDim.x + threadIdx.x;
    if (i >= N) return;
    int v = inv[i];
    if (v < 0) return;
    float y0[32];
    feats_y0(pts, i, meanArr, v, w0, y0);
#pragma unroll
    for (int c = 0; c < 32; c++) {
        float e = fmaxf(y0[c] * sb0[c] + sb0[32 + c], 0.0f);
        if (e > 0.0f)   // relu>=0 and init==0 -> uint max == float max; skip zeros
            atomicMax(&xmax[(size_t)v * 32 + c], __float_as_uint(e));
    }
}

// ---------------------------------------------------------------- build x1[64]
__device__ __forceinline__ void build_x1(const float* __restrict__ pts, int i,
                                         const float* __restrict__ meanArr, int v,
                                         const float* __restrict__ w0,
                                         const float* __restrict__ sb0,
                                         const float* __restrict__ xmaxF, float x1[64])
{
    feats_y0(pts, i, meanArr, v, w0, x1);   // x1[0..31] = y0
#pragma unroll
    for (int c = 0; c < 32; c++) x1[c] = fmaxf(x1[c] * sb0[c] + sb0[32 + c], 0.0f);
    const float4* xr = reinterpret_cast<const float4*>(xmaxF + (size_t)v * 32);
#pragma unroll
    for (int q = 0; q < 8; q++) {
        float4 t = xr[q];
        x1[32 + q * 4 + 0] = t.x;
        x1[32 + q * 4 + 1] = t.y;
        x1[32 + q * 4 + 2] = t.z;
        x1[32 + q * 4 + 3] = t.w;
    }
}

// ---------------------------------------------------------------- K6: BN1 stats
__global__ void k6_stats1(const float* __restrict__ pts, const float* __restrict__ w0,
                          const float* __restrict__ w1, const int* __restrict__ inv,
                          const float* __restrict__ meanArr, const float* __restrict__ sb0,
                          const float* __restrict__ xmaxF, float* __restrict__ stats1,
                          int N)
{
    float a0s = 0.0f, a0q = 0.0f, a1s = 0.0f, a1q = 0.0f;   // lane-held channels: lane, lane+64
    int lane = threadIdx.x & 63;
    int gid = blockIdx.x * blockDim.x + threadIdx.x;
    int gsz = gridDim.x * blockDim.x;
    // uniform trip count: every lane runs every iteration (shuffles need full wave)
    for (int base = 0; base < N; base += gsz) {
        int i = base + gid;
        bool in = (i < N);
        int ic = in ? i : (N - 1);
        int v = in ? inv[ic] : -1;
        bool on = (v >= 0);
        int vv = on ? v : 0;
        float x1[64];
        build_x1(pts, ic, meanArr, vv, w0, sb0, xmaxF, x1);
        if (!on) {
#pragma unroll
            for (int k = 0; k < 64; k++) x1[k] = 0.0f;
        }
#pragma unroll 1
        for (int ch = 0; ch < 4; ch++) {      // keep body = 2048 FMA (I$)
            int cb = ch * 32;
            float acc[32];
#pragma unroll
            for (int j = 0; j < 32; j++) acc[j] = 0.0f;
#pragma unroll
            for (int k = 0; k < 64; k++) {
                float xk = x1[k];
#pragma unroll
                for (int j = 0; j < 32; j++)
                    acc[j] += xk * w1[k * 128 + cb + j];   // uniform index -> s_load
            }
#pragma unroll
            for (int j = 0; j < 32; j++) {
                float s = acc[j], q = acc[j] * acc[j];
#pragma unroll
                for (int msk = 1; msk < 64; msk <<= 1) {
                    s += __shfl_xor(s, msk);
                    q += __shfl_xor(q, msk);
                }
                int c = cb + j;
                if (lane == (c & 63)) {
                    if (c < 64) { a0s += s; a0q += q; }
                    else        { a1s += s; a1q += q; }
                }
            }
        }
    }
    atomicAdd(&stats1[lane],            a0s);
    atomicAdd(&stats1[64 + lane],       a1s);
    atomicAdd(&stats1[128 + lane],      a0q);
    atomicAdd(&stats1[128 + 64 + lane], a1q);
}

// ---------------------------------------------------------------- K8: output pass
__global__ void k8_out(const float* __restrict__ pts, const float* __restrict__ w0,
                       const float* __restrict__ w1, const int* __restrict__ inv,
                       const float* __restrict__ meanArr, const float* __restrict__ sb0,
                       const float* __restrict__ sb1, const float* __restrict__ xmaxF,
                       unsigned int* __restrict__ out, int N)
{
    int i = blockIdx.x * blockDim.x + threadIdx.x;
    if (i >= N) return;
    int v = inv[i];
    if (v < 0) return;
    float x1[64];
    build_x1(pts, i, meanArr, v, w0, sb0, xmaxF, x1);
#pragma unroll 1
    for (int ch = 0; ch < 4; ch++) {
        int cb = ch * 32;
        float acc[32];
#pragma unroll
        for (int j = 0; j < 32; j++) acc[j] = 0.0f;
#pragma unroll
        for (int k = 0; k < 64; k++) {
            float xk = x1[k];
#pragma unroll
            for (int j = 0; j < 32; j++)
                acc[j] += xk * w1[k * 128 + cb + j];
        }
#pragma unroll
        for (int j = 0; j < 32; j++) {
            int c = cb + j;
            float e = fmaxf(acc[j] * sb1[c] + sb1[128 + c], 0.0f);
            if (e > 0.0f)
                atomicMax(&out[(size_t)v * 128 + c], __float_as_uint(e));
        }
    }
}

// ---------------------------------------------------------------- launch
extern "C" void kernel_launch(void* const* d_in, const int* in_sizes, int n_in,
                              void* d_out, int out_size, void* d_ws, size_t ws_size,
                              hipStream_t stream)
{
    const float* pts = (const float*)d_in[0];
    const float* w0  = (const float*)d_in[1];
    const float* g0  = (const float*)d_in[2];
    const float* b0  = (const float*)d_in[3];
    const float* w1  = (const float*)d_in[4];
    const float* g1  = (const float*)d_in[5];
    const float* b1  = (const float*)d_in[6];

    int N = in_sizes[0] / 5;
    int V = out_size / 132;          // pillar_feat V*128 + pillar_coords V*4

    char* ws = (char*)d_ws;
    // layout (bytes)
    size_t offInv  = 0;                               // N ints
    size_t offA    = ((size_t)N * 4 + 255) & ~(size_t)255;
    int*   inv       = (int*)(ws + offInv);
    int*   cnt       = (int*)(ws + offA);                       // M ints
    float* sums      = (float*)(ws + offA + 880000);            // 3M floats
    int*   chunkTot  = (int*)(ws + offA + 3520000);             // 1024 ints
    int*   chunkBase = (int*)(ws + offA + 3524096);             // 1024 ints
    float* stats     = (float*)(ws + offA + 3528192);           // 320 floats (bn0:64 | bn1:256)
    int*   np        = (int*)(ws + offA + 3529472);             // 1 int
    size_t zeroBytes = 3529476;                                 // cnt..np inclusive
    size_t offB      = offA + 3529728;
    float* sb0     = (float*)(ws + offB);                       // 64 floats
    float* sb1     = (float*)(ws + offB + 256);                 // 256 floats
    int*   idxArr  = (int*)(ws + offB + 1280);                  // M ints
    float* meanArr = (float*)(ws + offB + 1280 + 880000);       // 3M floats
    float* xmaxB   = (float*)(ws + offB + 1280 + 880000 + 2640000); // M*32 floats

    hipMemsetAsync(ws + offA, 0, zeroBytes, stream);
    hipMemsetAsync(xmaxB, 0, (size_t)M_IDS * 32 * 4, stream);
    hipMemsetAsync(d_out, 0, (size_t)V * 128 * 4, stream);

    int blocksN = (N + 255) / 256;
    float* outF = (float*)d_out;

    k1_count<<<blocksN, 256, 0, stream>>>(pts, inv, cnt, sums, N);
    k2a_chunktot<<<NCHUNK, CH, 0, stream>>>(cnt, chunkTot, np);
    k2b_scan<<<1, 1024, 0, stream>>>(chunkTot, chunkBase);
    k2c_index<<<NCHUNK, CH, 0, stream>>>(cnt, sums, chunkBase, idxArr, meanArr,
                                         outF + (size_t)V * 128);
    k3_stats0<<<768, 256, 0, stream>>>(pts, w0, idxArr, inv, meanArr, stats, N);
    k_bnfin<<<1, 32, 0, stream>>>(stats, np, g0, b0, sb0, 32);
    k5_xmax<<<blocksN, 256, 0, stream>>>(pts, w0, inv, meanArr, sb0,
                                         (unsigned int*)xmaxB, N);
    k6_stats1<<<768, 256, 0, stream>>>(pts, w0, w1, inv, meanArr, sb0, xmaxB,
                                       stats + 64, N);
    k_bnfin<<<1, 128, 0, stream>>>(stats + 64, np, g1, b1, sb1, 128);
    k8_out<<<blocksN, 256, 0, stream>>>(pts, w0, w1, inv, meanArr, sb0, sb1, xmaxB,
                                        (unsigned int*)d_out, N);
}

// Round 2
// 11813.150 us; speedup vs baseline: 1.0245x; 1.0245x over previous
//
#include <hip/hip_runtime.h>
#include <cstdint>
#include <cstddef>

// ConvVFE: voxelize -> per-voxel mean -> MLP(10->32)+BN+ReLU -> voxel max
// -> concat -> MLP(64->128)+BN+ReLU -> voxel max ; plus voxel coords.
//
// merge id = b*55000 + cx*250 + cy (+cz, cz==0), bounded by 220000 ->
// dense histogram + ordered prefix scan reproduces jnp.unique sorted order.
//
// R2: __launch_bounds__ on the fat kernels. Round-1 counters showed
// VGPR_Count=64 + 383MB WRITE_SIZE on k6 => full x1[64]/acc[32] scratch
// spill. (256,2) lifts the VGPR cap to 256 so the working set stays
// resident.

constexpr int M_IDS  = 220000;            // 4 * 220 * 250 * 1
constexpr int CH     = 256;               // scan chunk
constexpr int NCHUNK = (M_IDS + CH - 1) / CH;   // 860

// ---------------------------------------------------------------- K1: histogram
__global__ void k1_count(const float* __restrict__ pts, int* __restrict__ inv,
                         int* __restrict__ cnt, float* __restrict__ sums, int N)
{
    int i = blockIdx.x * blockDim.x + threadIdx.x;
    if (i >= N) return;
    const float* p = pts + (size_t)i * 5;
    float b = p[0], x = p[1], y = p[2], z = p[3];
    // IEEE fp32 division to bit-match numpy's floor((p - pcr)/vsz)
    float fx = floorf((x - 0.0f) / 0.32f);
    float fy = floorf((y + 40.0f) / 0.32f);
    float fz = floorf((z + 3.0f) / 4.0f);
    bool ok = (fx >= 0.0f) && (fx < 220.0f) && (fy >= 0.0f) && (fy < 250.0f) &&
              (fz >= 0.0f) && (fz < 1.0f);
    if (!ok) { inv[i] = -1; return; }
    int merge = (int)b * 55000 + (int)fx * 250 + (int)fy + (int)fz;
    inv[i] = merge;
    atomicAdd(&cnt[merge], 1);
    atomicAdd(&sums[merge * 3 + 0], x);
    atomicAdd(&sums[merge * 3 + 1], y);
    atomicAdd(&sums[merge * 3 + 2], z);
}

// ---------------------------------------------------------------- K2: ordered compaction
__global__ void k2a_chunktot(const int* __restrict__ cnt, int* __restrict__ chunkTot,
                             int* __restrict__ np)
{
    __shared__ int so[CH], sc[CH];
    int tid = threadIdx.x;
    int id = blockIdx.x * CH + tid;
    int c = (id < M_IDS) ? cnt[id] : 0;
    so[tid] = (c > 0) ? 1 : 0;
    sc[tid] = c;
    __syncthreads();
    for (int s = CH / 2; s > 0; s >>= 1) {
        if (tid < s) { so[tid] += so[tid + s]; sc[tid] += sc[tid + s]; }
        __syncthreads();
    }
    if (tid == 0) { chunkTot[blockIdx.x] = so[0]; atomicAdd(np, sc[0]); }
}

__global__ void k2b_scan(const int* __restrict__ chunkTot, int* __restrict__ chunkBase)
{
    __shared__ int ls[1024];
    int t = threadIdx.x;
    int v = (t < NCHUNK) ? chunkTot[t] : 0;
    ls[t] = v;
    __syncthreads();
    for (int off = 1; off < 1024; off <<= 1) {
        int x = (t >= off) ? ls[t - off] : 0;
        __syncthreads();
        ls[t] += x;
        __syncthreads();
    }
    chunkBase[t] = ls[t] - v;   // exclusive
}

__global__ void k2c_index(const int* __restrict__ cnt, const float* __restrict__ sums,
                          const int* __restrict__ chunkBase, int* __restrict__ idxArr,
                          float* __restrict__ meanArr, float* __restrict__ outCoords)
{
    __shared__ int ls[CH];
    int tid = threadIdx.x;
    int id = blockIdx.x * CH + tid;
    int c = (id < M_IDS) ? cnt[id] : 0;
    int occ = (c > 0) ? 1 : 0;
    ls[tid] = occ;
    __syncthreads();
    for (int off = 1; off < CH; off <<= 1) {
        int x = (tid >= off) ? ls[tid - off] : 0;
        __syncthreads();
        ls[tid] += x;
        __syncthreads();
    }
    int g = chunkBase[blockIdx.x] + ls[tid] - occ;
    if (id < M_IDS) idxArr[id] = g;
    if (occ) {
        float fc = (float)c;
        meanArr[(size_t)g * 3 + 0] = sums[(size_t)id * 3 + 0] / fc;
        meanArr[(size_t)g * 3 + 1] = sums[(size_t)id * 3 + 1] / fc;
        meanArr[(size_t)g * 3 + 2] = sums[(size_t)id * 3 + 2] / fc;
        int b  = id / 55000;
        int rm = id % 55000;
        int cx = rm / 250;
        int cy = rm % 250;
        outCoords[(size_t)g * 4 + 0] = (float)b;
        outCoords[(size_t)g * 4 + 1] = 0.0f;
        outCoords[(size_t)g * 4 + 2] = (float)cy;
        outCoords[(size_t)g * 4 + 3] = (float)cx;
    }
}

// ---------------------------------------------------------------- feats -> y0 (10x32)
__device__ __forceinline__ void feats_y0(const float* __restrict__ pts, int i,
                                         const float* __restrict__ meanArr, int v,
                                         const float* __restrict__ w0, float y0[32])
{
    const float* p = pts + (size_t)i * 5;
    float x = p[1], y = p[2], z = p[3], it = p[4];
    float fx = floorf((x - 0.0f) / 0.32f);
    float fy = floorf((y + 40.0f) / 0.32f);
    float f[10];
    f[0] = x; f[1] = y; f[2] = z; f[3] = it;
    f[4] = x - meanArr[(size_t)v * 3 + 0];
    f[5] = y - meanArr[(size_t)v * 3 + 1];
    f[6] = z - meanArr[(size_t)v * 3 + 2];
    f[7] = x - (fx * 0.32f + 0.16f);
    f[8] = y - (fy * 0.32f + (-39.84f));
    f[9] = z + 1.0f;                        // z - Z_OFF, Z_OFF = -1.0
#pragma unroll
    for (int c = 0; c < 32; c++) y0[c] = 0.0f;
#pragma unroll
    for (int d = 0; d < 10; d++) {
        float fd = f[d];
#pragma unroll
        for (int c = 0; c < 32; c++) y0[c] += fd * w0[d * 32 + c];   // w0 uniform -> s_load
    }
}

// ---------------------------------------------------------------- K3: BN0 stats (+inv compaction)
__global__ __launch_bounds__(256, 2)
void k3_stats0(const float* __restrict__ pts, const float* __restrict__ w0,
               const int* __restrict__ idxArr, int* __restrict__ inv,
               const float* __restrict__ meanArr, float* __restrict__ stats0,
               int N)
{
    float rs[32], rq[32];
#pragma unroll
    for (int c = 0; c < 32; c++) { rs[c] = 0.0f; rq[c] = 0.0f; }
    int gid = blockIdx.x * blockDim.x + threadIdx.x;
    int gsz = gridDim.x * blockDim.x;
    for (int i = gid; i < N; i += gsz) {
        int m = inv[i];
        int v = (m >= 0) ? idxArr[m] : -1;
        inv[i] = v;
        if (v < 0) continue;
        float y0[32];
        feats_y0(pts, i, meanArr, v, w0, y0);
#pragma unroll
        for (int c = 0; c < 32; c++) { rs[c] += y0[c]; rq[c] += y0[c] * y0[c]; }
    }
    // wave allreduce after loop (all lanes converged here)
    int lane = threadIdx.x & 63;
#pragma unroll
    for (int c = 0; c < 32; c++) {
        float s = rs[c], q = rq[c];
#pragma unroll
        for (int msk = 1; msk < 64; msk <<= 1) {
            s += __shfl_xor(s, msk);
            q += __shfl_xor(q, msk);
        }
        if (lane == c)      atomicAdd(&stats0[c], s);
        if (lane == 32 + c) atomicAdd(&stats0[32 + c], q);
    }
}

// ---------------------------------------------------------------- BN finalize (scale/bias)
__global__ void k_bnfin(const float* __restrict__ stats, const int* __restrict__ np,
                        const float* __restrict__ g, const float* __restrict__ b,
                        float* __restrict__ sb, int C)
{
    int c = blockIdx.x * blockDim.x + threadIdx.x;
    if (c >= C) return;
    float n   = (float)(*np);
    float mu  = stats[c] / n;
    float var = stats[C + c] / n - mu * mu;
    float s   = g[c] / sqrtf(var + 1e-3f);
    sb[c]     = s;
    sb[C + c] = b[c] - mu * s;
}

// ---------------------------------------------------------------- K5: x0 voxel max
__global__ __launch_bounds__(256, 4)
void k5_xmax(const float* __restrict__ pts, const float* __restrict__ w0,
             const int* __restrict__ inv, const float* __restrict__ meanArr,
             const float* __restrict__ sb0, unsigned int* __restrict__ xmax,
             int N)
{
    int i = blockIdx.x * blockDim.x + threadIdx.x;
    if (i >= N) return;
    int v = inv[i];
    if (v < 0) return;
    float y0[32];
    feats_y0(pts, i, meanArr, v, w0, y0);
#pragma unroll
    for (int c = 0; c < 32; c++) {
        float e = fmaxf(y0[c] * sb0[c] + sb0[32 + c], 0.0f);
        if (e > 0.0f)   // relu>=0 and init==0 -> uint max == float max; skip zeros
            atomicMax(&xmax[(size_t)v * 32 + c], __float_as_uint(e));
    }
}

// ---------------------------------------------------------------- build x1[64]
__device__ __forceinline__ void build_x1(const float* __restrict__ pts, int i,
                                         const float* __restrict__ meanArr, int v,
                                         const float* __restrict__ w0,
                                         const float* __restrict__ sb0,
                                         const float* __restrict__ xmaxF, float x1[64])
{
    feats_y0(pts, i, meanArr, v, w0, x1);   // x1[0..31] = y0
#pragma unroll
    for (int c = 0; c < 32; c++) x1[c] = fmaxf(x1[c] * sb0[c] + sb0[32 + c], 0.0f);
    const float4* xr = reinterpret_cast<const float4*>(xmaxF + (size_t)v * 32);
#pragma unroll
    for (int q = 0; q < 8; q++) {
        float4 t = xr[q];
        x1[32 + q * 4 + 0] = t.x;
        x1[32 + q * 4 + 1] = t.y;
        x1[32 + q * 4 + 2] = t.z;
        x1[32 + q * 4 + 3] = t.w;
    }
}

// ---------------------------------------------------------------- K6: BN1 stats
__global__ __launch_bounds__(256, 2)
void k6_stats1(const float* __restrict__ pts, const float* __restrict__ w0,
               const float* __restrict__ w1, const int* __restrict__ inv,
               const float* __restrict__ meanArr, const float* __restrict__ sb0,
               const float* __restrict__ xmaxF, float* __restrict__ stats1,
               int N)
{
    float a0s = 0.0f, a0q = 0.0f, a1s = 0.0f, a1q = 0.0f;   // lane-held channels: lane, lane+64
    int lane = threadIdx.x & 63;
    int gid = blockIdx.x * blockDim.x + threadIdx.x;
    int gsz = gridDim.x * blockDim.x;
    // uniform trip count: every lane runs every iteration (shuffles need full wave)
    for (int base = 0; base < N; base += gsz) {
        int i = base + gid;
        bool in = (i < N);
        int ic = in ? i : (N - 1);
        int v = in ? inv[ic] : -1;
        bool on = (v >= 0);
        int vv = on ? v : 0;
        float x1[64];
        build_x1(pts, ic, meanArr, vv, w0, sb0, xmaxF, x1);
        if (!on) {
#pragma unroll
            for (int k = 0; k < 64; k++) x1[k] = 0.0f;
        }
#pragma unroll 1
        for (int ch = 0; ch < 4; ch++) {      // keep body = 2048 FMA (I$)
            int cb = ch * 32;
            float acc[32];
#pragma unroll
            for (int j = 0; j < 32; j++) acc[j] = 0.0f;
#pragma unroll
            for (int k = 0; k < 64; k++) {
                float xk = x1[k];
#pragma unroll
                for (int j = 0; j < 32; j++)
                    acc[j] += xk * w1[k * 128 + cb + j];   // uniform index -> s_load
            }
#pragma unroll
            for (int j = 0; j < 32; j++) {
                float s = acc[j], q = acc[j] * acc[j];
#pragma unroll
                for (int msk = 1; msk < 64; msk <<= 1) {
                    s += __shfl_xor(s, msk);
                    q += __shfl_xor(q, msk);
                }
                int c = cb + j;
                if (lane == (c & 63)) {
                    if (c < 64) { a0s += s; a0q += q; }
                    else        { a1s += s; a1q += q; }
                }
            }
        }
    }
    atomicAdd(&stats1[lane],            a0s);
    atomicAdd(&stats1[64 + lane],       a1s);
    atomicAdd(&stats1[128 + lane],      a0q);
    atomicAdd(&stats1[128 + 64 + lane], a1q);
}

// ---------------------------------------------------------------- K8: output pass
__global__ __launch_bounds__(256, 2)
void k8_out(const float* __restrict__ pts, const float* __restrict__ w0,
            const float* __restrict__ w1, const int* __restrict__ inv,
            const float* __restrict__ meanArr, const float* __restrict__ sb0,
            const float* __restrict__ sb1, const float* __restrict__ xmaxF,
            unsigned int* __restrict__ out, int N)
{
    int i = blockIdx.x * blockDim.x + threadIdx.x;
    if (i >= N) return;
    int v = inv[i];
    if (v < 0) return;
    float x1[64];
    build_x1(pts, i, meanArr, v, w0, sb0, xmaxF, x1);
#pragma unroll 1
    for (int ch = 0; ch < 4; ch++) {
        int cb = ch * 32;
        float acc[32];
#pragma unroll
        for (int j = 0; j < 32; j++) acc[j] = 0.0f;
#pragma unroll
        for (int k = 0; k < 64; k++) {
            float xk = x1[k];
#pragma unroll
            for (int j = 0; j < 32; j++)
                acc[j] += xk * w1[k * 128 + cb + j];
        }
#pragma unroll
        for (int j = 0; j < 32; j++) {
            int c = cb + j;
            float e = fmaxf(acc[j] * sb1[c] + sb1[128 + c], 0.0f);
            if (e > 0.0f)
                atomicMax(&out[(size_t)v * 128 + c], __float_as_uint(e));
        }
    }
}

// ---------------------------------------------------------------- launch
extern "C" void kernel_launch(void* const* d_in, const int* in_sizes, int n_in,
                              void* d_out, int out_size, void* d_ws, size_t ws_size,
                              hipStream_t stream)
{
    const float* pts = (const float*)d_in[0];
    const float* w0  = (const float*)d_in[1];
    const float* g0  = (const float*)d_in[2];
    const float* b0  = (const float*)d_in[3];
    const float* w1  = (const float*)d_in[4];
    const float* g1  = (const float*)d_in[5];
    const float* b1  = (const float*)d_in[6];

    int N = in_sizes[0] / 5;
    int V = out_size / 132;          // pillar_feat V*128 + pillar_coords V*4

    char* ws = (char*)d_ws;
    // layout (bytes)
    size_t offInv  = 0;                               // N ints
    size_t offA    = ((size_t)N * 4 + 255) & ~(size_t)255;
    int*   inv       = (int*)(ws + offInv);
    int*   cnt       = (int*)(ws + offA);                       // M ints
    float* sums      = (float*)(ws + offA + 880000);            // 3M floats
    int*   chunkTot  = (int*)(ws + offA + 3520000);             // 1024 ints
    int*   chunkBase = (int*)(ws + offA + 3524096);             // 1024 ints
    float* stats     = (float*)(ws + offA + 3528192);           // 320 floats (bn0:64 | bn1:256)
    int*   np        = (int*)(ws + offA + 3529472);             // 1 int
    size_t zeroBytes = 3529476;                                 // cnt..np inclusive
    size_t offB      = offA + 3529728;
    float* sb0     = (float*)(ws + offB);                       // 64 floats
    float* sb1     = (float*)(ws + offB + 256);                 // 256 floats
    int*   idxArr  = (int*)(ws + offB + 1280);                  // M ints
    float* meanArr = (float*)(ws + offB + 1280 + 880000);       // 3M floats
    float* xmaxB   = (float*)(ws + offB + 1280 + 880000 + 2640000); // M*32 floats

    hipMemsetAsync(ws + offA, 0, zeroBytes, stream);
    hipMemsetAsync(xmaxB, 0, (size_t)M_IDS * 32 * 4, stream);
    hipMemsetAsync(d_out, 0, (size_t)V * 128 * 4, stream);

    int blocksN = (N + 255) / 256;
    float* outF = (float*)d_out;

    k1_count<<<blocksN, 256, 0, stream>>>(pts, inv, cnt, sums, N);
    k2a_chunktot<<<NCHUNK, CH, 0, stream>>>(cnt, chunkTot, np);
    k2b_scan<<<1, 1024, 0, stream>>>(chunkTot, chunkBase);
    k2c_index<<<NCHUNK, CH, 0, stream>>>(cnt, sums, chunkBase, idxArr, meanArr,
                                         outF + (size_t)V * 128);
    k3_stats0<<<768, 256, 0, stream>>>(pts, w0, idxArr, inv, meanArr, stats, N);
    k_bnfin<<<1, 32, 0, stream>>>(stats, np, g0, b0, sb0, 32);
    k5_xmax<<<blocksN, 256, 0, stream>>>(pts, w0, inv, meanArr, sb0,
                                         (unsigned int*)xmaxB, N);
    k6_stats1<<<768, 256, 0, stream>>>(pts, w0, w1, inv, meanArr, sb0, xmaxB,
                                       stats + 64, N);
    k_bnfin<<<1, 128, 0, stream>>>(stats + 64, np, g1, b1, sb1, 128);
    k8_out<<<blocksN, 256, 0, stream>>>(pts, w0, w1, inv, meanArr, sb0, sb1, xmaxB,
                                        (unsigned int*)d_out, N);
}

// Round 3
// 3757.698 us; speedup vs baseline: 3.2207x; 3.1437x over previous
//
#include <hip/hip_runtime.h>
#include <cstdint>
#include <cstddef>

// ConvVFE: voxelize -> per-voxel mean -> MLP(10->32)+BN+ReLU -> voxel max
// -> concat -> MLP(64->128)+BN+ReLU -> voxel max ; plus voxel coords.
//
// R3: rounds 1-2 showed the monolithic per-point kernels spill their
// x1[64]/acc[32] working sets to scratch (340MB WRITE_SIZE, ~30x VALU
// bloat) regardless of launch_bounds. Restructure: materialize x1^T
// (channel-major bf16, rows 0..31 = bn0(relu(y0)), rows 32..63 = xmax
// gather) and run the 64->128 layer as a tiled LDS GEMM with a 4x8
// register tile per thread (acc fits trivially in VGPRs).

constexpr int M_IDS  = 220000;            // 4 * 220 * 250 * 1
constexpr int CH     = 256;
constexpr int NCHUNK = (M_IDS + CH - 1) / CH;   // 860

__device__ __forceinline__ uint16_t f2b(float f) {
    uint32_t u = __float_as_uint(f);
    u += 0x7fffu + ((u >> 16) & 1u);      // RNE
    return (uint16_t)(u >> 16);
}
__device__ __forceinline__ float b2f(uint16_t h) {
    return __uint_as_float(((uint32_t)h) << 16);
}

// ---------------------------------------------------------------- K1: histogram
__global__ void k1_count(const float* __restrict__ pts, int* __restrict__ inv,
                         int* __restrict__ cnt, float* __restrict__ sums, int N)
{
    int i = blockIdx.x * blockDim.x + threadIdx.x;
    if (i >= N) return;
    const float* p = pts + (size_t)i * 5;
    float b = p[0], x = p[1], y = p[2], z = p[3];
    // IEEE fp32 division to bit-match numpy's floor((p - pcr)/vsz)
    float fx = floorf((x - 0.0f) / 0.32f);
    float fy = floorf((y + 40.0f) / 0.32f);
    float fz = floorf((z + 3.0f) / 4.0f);
    bool ok = (fx >= 0.0f) && (fx < 220.0f) && (fy >= 0.0f) && (fy < 250.0f) &&
              (fz >= 0.0f) && (fz < 1.0f);
    if (!ok) { inv[i] = -1; return; }
    int merge = (int)b * 55000 + (int)fx * 250 + (int)fy + (int)fz;
    inv[i] = merge;
    atomicAdd(&cnt[merge], 1);
    atomicAdd(&sums[merge * 3 + 0], x);
    atomicAdd(&sums[merge * 3 + 1], y);
    atomicAdd(&sums[merge * 3 + 2], z);
}

// ---------------------------------------------------------------- K2: ordered compaction
__global__ void k2a_chunktot(const int* __restrict__ cnt, int* __restrict__ chunkTot,
                             int* __restrict__ np)
{
    __shared__ int so[CH], sc[CH];
    int tid = threadIdx.x;
    int id = blockIdx.x * CH + tid;
    int c = (id < M_IDS) ? cnt[id] : 0;
    so[tid] = (c > 0) ? 1 : 0;
    sc[tid] = c;
    __syncthreads();
    for (int s = CH / 2; s > 0; s >>= 1) {
        if (tid < s) { so[tid] += so[tid + s]; sc[tid] += sc[tid + s]; }
        __syncthreads();
    }
    if (tid == 0) { chunkTot[blockIdx.x] = so[0]; atomicAdd(np, sc[0]); }
}

__global__ void k2b_scan(const int* __restrict__ chunkTot, int* __restrict__ chunkBase)
{
    __shared__ int ls[1024];
    int t = threadIdx.x;
    int v = (t < NCHUNK) ? chunkTot[t] : 0;
    ls[t] = v;
    __syncthreads();
    for (int off = 1; off < 1024; off <<= 1) {
        int x = (t >= off) ? ls[t - off] : 0;
        __syncthreads();
        ls[t] += x;
        __syncthreads();
    }
    chunkBase[t] = ls[t] - v;   // exclusive
}

__global__ void k2c_index(const int* __restrict__ cnt, const float* __restrict__ sums,
                          const int* __restrict__ chunkBase, int* __restrict__ idxArr,
                          float* __restrict__ meanArr, float* __restrict__ outCoords)
{
    __shared__ int ls[CH];
    int tid = threadIdx.x;
    int id = blockIdx.x * CH + tid;
    int c = (id < M_IDS) ? cnt[id] : 0;
    int occ = (c > 0) ? 1 : 0;
    ls[tid] = occ;
    __syncthreads();
    for (int off = 1; off < CH; off <<= 1) {
        int x = (tid >= off) ? ls[tid - off] : 0;
        __syncthreads();
        ls[tid] += x;
        __syncthreads();
    }
    int g = chunkBase[blockIdx.x] + ls[tid] - occ;
    if (id < M_IDS) idxArr[id] = g;
    if (occ) {
        float fc = (float)c;
        meanArr[(size_t)g * 3 + 0] = sums[(size_t)id * 3 + 0] / fc;
        meanArr[(size_t)g * 3 + 1] = sums[(size_t)id * 3 + 1] / fc;
        meanArr[(size_t)g * 3 + 2] = sums[(size_t)id * 3 + 2] / fc;
        int b  = id / 55000;
        int rm = id % 55000;
        int cx = rm / 250;
        int cy = rm % 250;
        outCoords[(size_t)g * 4 + 0] = (float)b;
        outCoords[(size_t)g * 4 + 1] = 0.0f;
        outCoords[(size_t)g * 4 + 2] = (float)cy;
        outCoords[(size_t)g * 4 + 3] = (float)cx;
    }
}

// ---------------------------------------------------------------- kA: feats @ w0 -> X rows 0..31 (bf16, channel-major)
__global__ __launch_bounds__(256, 2)
void kA_y0(const float* __restrict__ pts, const float* __restrict__ w0,
           const int* __restrict__ idxArr, int* __restrict__ inv,
           const float* __restrict__ meanArr, uint16_t* __restrict__ Xb,
           int N, int Npad)
{
    int i = blockIdx.x * 256 + threadIdx.x;   // grid sized to Npad exactly
    float y0[32];
#pragma unroll
    for (int c = 0; c < 32; c++) y0[c] = 0.0f;
    if (i < N) {
        int m = inv[i];
        int v = (m >= 0) ? idxArr[m] : -1;
        inv[i] = v;
        if (v >= 0) {
            const float* p = pts + (size_t)i * 5;
            float x = p[1], y = p[2], z = p[3], it = p[4];
            float fx = floorf((x - 0.0f) / 0.32f);
            float fy = floorf((y + 40.0f) / 0.32f);
            float f[10];
            f[0] = x; f[1] = y; f[2] = z; f[3] = it;
            f[4] = x - meanArr[(size_t)v * 3 + 0];
            f[5] = y - meanArr[(size_t)v * 3 + 1];
            f[6] = z - meanArr[(size_t)v * 3 + 2];
            f[7] = x - (fx * 0.32f + 0.16f);
            f[8] = y - (fy * 0.32f - 39.84f);
            f[9] = z + 1.0f;
#pragma unroll
            for (int d = 0; d < 10; d++) {
                float fd = f[d];
#pragma unroll
                for (int c = 0; c < 32; c++) y0[c] += fd * w0[d * 32 + c];
            }
        }
    }
#pragma unroll
    for (int c = 0; c < 32; c++) Xb[(size_t)c * Npad + i] = f2b(y0[c]);
}

// ---------------------------------------------------------------- kB: BN0 stats (row reduction)
__global__ __launch_bounds__(256, 4)
void kB_stats0(const uint16_t* __restrict__ Xb, float* __restrict__ stats0,
               int N, int Npad)
{
    int c = blockIdx.y;
    const uint16_t* row = Xb + (size_t)c * Npad;
    float s = 0.0f, q = 0.0f;
    for (int i4 = (blockIdx.x * 256 + threadIdx.x) * 4; i4 < N;
         i4 += gridDim.x * 1024) {
        ushort4 u = *(const ushort4*)(row + i4);      // N%4==0
        float a0 = b2f(u.x), a1 = b2f(u.y), a2 = b2f(u.z), a3 = b2f(u.w);
        s += (a0 + a1) + (a2 + a3);
        q += (a0 * a0 + a1 * a1) + (a2 * a2 + a3 * a3);
    }
#pragma unroll
    for (int m = 1; m < 64; m <<= 1) { s += __shfl_xor(s, m); q += __shfl_xor(q, m); }
    if ((threadIdx.x & 63) == 0) {
        atomicAdd(&stats0[c], s);
        atomicAdd(&stats0[32 + c], q);
    }
}

// ---------------------------------------------------------------- BN finalize
__global__ void k_bnfin(const float* __restrict__ stats, const int* __restrict__ np,
                        const float* __restrict__ g, const float* __restrict__ b,
                        float* __restrict__ sb, int C)
{
    int c = blockIdx.x * blockDim.x + threadIdx.x;
    if (c >= C) return;
    float n   = (float)(*np);
    float mu  = stats[c] / n;
    float var = stats[C + c] / n - mu * mu;
    float s   = g[c] / sqrtf(var + 1e-3f);
    sb[c]     = s;
    sb[C + c] = b[c] - mu * s;
}

// ---------------------------------------------------------------- kD: x0 = relu(bn0(y0)) in place + xmax atomics
__global__ __launch_bounds__(256, 4)
void kD_apply0(uint16_t* __restrict__ Xb, const int* __restrict__ inv,
               const float* __restrict__ sb0, float* __restrict__ xmaxF,
               int N, int Npad)
{
    int c = blockIdx.y;
    int i4 = (blockIdx.x * 256 + threadIdx.x) * 4;
    if (i4 >= Npad) return;
    uint16_t* row = Xb + (size_t)c * Npad;
    float sc = sb0[c], bc = sb0[32 + c];
    ushort4 u = *(const ushort4*)(row + i4);
    int4 vv = make_int4(-1, -1, -1, -1);
    if (i4 < N) vv = *(const int4*)(inv + i4);        // N%4==0
    int vs[4] = {vv.x, vv.y, vv.z, vv.w};
    uint16_t hv[4] = {u.x, u.y, u.z, u.w};
    ushort4 o;
    uint16_t* op = (uint16_t*)&o;
#pragma unroll
    for (int j = 0; j < 4; j++) {
        float e = 0.0f;
        if (i4 + j < N && vs[j] >= 0) {
            e = fmaxf(b2f(hv[j]) * sc + bc, 0.0f);
            if (e > 0.0f) {                           // relu>=0, init 0
                size_t a = (size_t)vs[j] * 32 + c;
                float cur = xmaxF[a];                  // stale-low safe (monotone)
                if (e > cur)
                    atomicMax((unsigned int*)&xmaxF[a], __float_as_uint(e));
            }
        }
        op[j] = f2b(e);
    }
    *(ushort4*)(row + i4) = o;
}

// ---------------------------------------------------------------- kE: X rows 32..63 = xmax[v] gather
__global__ __launch_bounds__(256, 4)
void kE_upper(uint16_t* __restrict__ Xb, const int* __restrict__ inv,
              const float* __restrict__ xmaxF, int N, int Npad)
{
    int c = blockIdx.y;
    int i4 = (blockIdx.x * 256 + threadIdx.x) * 4;
    if (i4 >= Npad) return;
    uint16_t* row = Xb + (size_t)(32 + c) * Npad;
    int4 vv = make_int4(-1, -1, -1, -1);
    if (i4 < N) vv = *(const int4*)(inv + i4);
    int vs[4] = {vv.x, vv.y, vv.z, vv.w};
    ushort4 o;
    uint16_t* op = (uint16_t*)&o;
#pragma unroll
    for (int j = 0; j < 4; j++) {
        float val = 0.0f;
        if (i4 + j < N && vs[j] >= 0) val = xmaxF[(size_t)vs[j] * 32 + c];
        op[j] = f2b(val);
    }
    *(ushort4*)(row + i4) = o;
}

// ---------------------------------------------------------------- GEMM tile staging: 64k x 64pts bf16 -> LDS fp32
__device__ __forceinline__ void stage_x1(const uint16_t* __restrict__ Xb, int Npad,
                                         int tb, float* x1s, int t)
{
    int k  = t >> 2;            // 0..63
    int cs = (t & 3) * 16;      // 0,16,32,48
    const uint16_t* src = Xb + (size_t)k * Npad + tb + cs;
    uint4 u0 = *(const uint4*)(src);
    uint4 u1 = *(const uint4*)(src + 8);
    float* dst = x1s + k * 64 + cs;
    dst[0]  = __uint_as_float(u0.x << 16); dst[1]  = __uint_as_float(u0.x & 0xffff0000u);
    dst[2]  = __uint_as_float(u0.y << 16); dst[3]  = __uint_as_float(u0.y & 0xffff0000u);
    dst[4]  = __uint_as_float(u0.z << 16); dst[5]  = __uint_as_float(u0.z & 0xffff0000u);
    dst[6]  = __uint_as_float(u0.w << 16); dst[7]  = __uint_as_float(u0.w & 0xffff0000u);
    dst[8]  = __uint_as_float(u1.x << 16); dst[9]  = __uint_as_float(u1.x & 0xffff0000u);
    dst[10] = __uint_as_float(u1.y << 16); dst[11] = __uint_as_float(u1.y & 0xffff0000u);
    dst[12] = __uint_as_float(u1.z << 16); dst[13] = __uint_as_float(u1.z & 0xffff0000u);
    dst[14] = __uint_as_float(u1.w << 16); dst[15] = __uint_as_float(u1.w & 0xffff0000u);
}

// ---------------------------------------------------------------- kF: GEMM stats pass (sum, sumsq of y1)
__global__ __launch_bounds__(256, 2)
void kF_gstats(const uint16_t* __restrict__ Xb, const float* __restrict__ w1,
               float* __restrict__ stats1, int Npad, int ntiles)
{
    __shared__ float w1s[64 * 128];
    __shared__ float x1s[64 * 64];
    int t = threadIdx.x;
    const float4* w1v = (const float4*)w1;
    float4* w1sv = (float4*)w1s;
    for (int j = t; j < 2048; j += 256) w1sv[j] = w1v[j];
    int p0 = (t & 15) * 4, c0 = (t >> 4) * 8;
    float s[8], q[8];
#pragma unroll
    for (int c = 0; c < 8; c++) { s[c] = 0.0f; q[c] = 0.0f; }
    for (int tile = blockIdx.x; tile < ntiles; tile += gridDim.x) {
        __syncthreads();
        stage_x1(Xb, Npad, tile * 64, x1s, t);
        __syncthreads();
        float acc[4][8];
#pragma unroll
        for (int p = 0; p < 4; p++)
#pragma unroll
            for (int c = 0; c < 8; c++) acc[p][c] = 0.0f;
#pragma unroll 8
        for (int k = 0; k < 64; k++) {
            float4 av = *(const float4*)&x1s[k * 64 + p0];
            float4 b0 = *(const float4*)&w1s[k * 128 + c0];
            float4 b1 = *(const float4*)&w1s[k * 128 + c0 + 4];
            float a[4] = {av.x, av.y, av.z, av.w};
            float b[8] = {b0.x, b0.y, b0.z, b0.w, b1.x, b1.y, b1.z, b1.w};
#pragma unroll
            for (int p = 0; p < 4; p++)
#pragma unroll
                for (int c = 0; c < 8; c++) acc[p][c] += a[p] * b[c];
        }
#pragma unroll
        for (int c = 0; c < 8; c++) {
            float ls = 0.0f, lq = 0.0f;
#pragma unroll
            for (int p = 0; p < 4; p++) { ls += acc[p][c]; lq += acc[p][c] * acc[p][c]; }
            s[c] += ls; q[c] += lq;
        }
    }
#pragma unroll
    for (int c = 0; c < 8; c++) {
#pragma unroll
        for (int m = 1; m < 16; m <<= 1) {
            s[c] += __shfl_xor(s[c], m);
            q[c] += __shfl_xor(q[c], m);
        }
    }
    if ((t & 15) == 0) {
#pragma unroll
        for (int c = 0; c < 8; c++) {
            atomicAdd(&stats1[c0 + c],       s[c]);
            atomicAdd(&stats1[128 + c0 + c], q[c]);
        }
    }
}

// ---------------------------------------------------------------- kH: GEMM apply pass + out atomicMax
__global__ __launch_bounds__(256, 2)
void kH_gout(const uint16_t* __restrict__ Xb, const float* __restrict__ w1,
             const int* __restrict__ inv, const float* __restrict__ sb1,
             unsigned int* __restrict__ out, int N, int Npad, int ntiles)
{
    __shared__ float w1s[64 * 128];
    __shared__ float x1s[64 * 64];
    int t = threadIdx.x;
    const float4* w1v = (const float4*)w1;
    float4* w1sv = (float4*)w1s;
    for (int j = t; j < 2048; j += 256) w1sv[j] = w1v[j];
    int p0 = (t & 15) * 4, c0 = (t >> 4) * 8;
    float sc[8], bc[8];
#pragma unroll
    for (int c = 0; c < 8; c++) { sc[c] = sb1[c0 + c]; bc[c] = sb1[128 + c0 + c]; }
    for (int tile = blockIdx.x; tile < ntiles; tile += gridDim.x) {
        __syncthreads();
        stage_x1(Xb, Npad, tile * 64, x1s, t);
        __syncthreads();
        float acc[4][8];
#pragma unroll
        for (int p = 0; p < 4; p++)
#pragma unroll
            for (int c = 0; c < 8; c++) acc[p][c] = 0.0f;
#pragma unroll 8
        for (int k = 0; k < 64; k++) {
            float4 av = *(const float4*)&x1s[k * 64 + p0];
            float4 b0 = *(const float4*)&w1s[k * 128 + c0];
            float4 b1 = *(const float4*)&w1s[k * 128 + c0 + 4];
            float a[4] = {av.x, av.y, av.z, av.w};
            float b[8] = {b0.x, b0.y, b0.z, b0.w, b1.x, b1.y, b1.z, b1.w};
#pragma unroll
            for (int p = 0; p < 4; p++)
#pragma unroll
                for (int c = 0; c < 8; c++) acc[p][c] += a[p] * b[c];
        }
        int tb = tile * 64;
#pragma unroll
        for (int p = 0; p < 4; p++) {
            int gp = tb + p0 + p;
            if (gp < N) {
                int v = inv[gp];
                if (v >= 0) {
                    size_t ob = (size_t)v * 128 + c0;
#pragma unroll
                    for (int c = 0; c < 8; c++) {
                        float e = fmaxf(acc[p][c] * sc[c] + bc[c], 0.0f);
                        if (e > 0.0f) {
                            float cur = __uint_as_float(out[ob + c]);
                            if (e > cur)
                                atomicMax(&out[ob + c], __float_as_uint(e));
                        }
                    }
                }
            }
        }
    }
}

// ---------------------------------------------------------------- launch
extern "C" void kernel_launch(void* const* d_in, const int* in_sizes, int n_in,
                              void* d_out, int out_size, void* d_ws, size_t ws_size,
                              hipStream_t stream)
{
    const float* pts = (const float*)d_in[0];
    const float* w0  = (const float*)d_in[1];
    const float* g0  = (const float*)d_in[2];
    const float* b0  = (const float*)d_in[3];
    const float* w1  = (const float*)d_in[4];
    const float* g1  = (const float*)d_in[5];
    const float* b1  = (const float*)d_in[6];

    int N    = in_sizes[0] / 5;
    int V    = out_size / 132;
    int Npad = (N + 255) & ~255;
    int ntiles = Npad / 64;

    char* ws = (char*)d_ws;
    size_t offA = ((size_t)N * 4 + 255) & ~(size_t)255;
    int*   inv       = (int*)ws;
    int*   cnt       = (int*)(ws + offA);
    float* sums      = (float*)(ws + offA + 880000);
    int*   chunkTot  = (int*)(ws + offA + 3520000);
    int*   chunkBase = (int*)(ws + offA + 3524096);
    float* stats     = (float*)(ws + offA + 3528192);   // bn0: 64 | bn1: 256
    int*   np        = (int*)(ws + offA + 3529472);
    size_t zeroBytes = 3529476;
    size_t offB      = offA + 3529728;
    float* sb0     = (float*)(ws + offB);
    float* sb1     = (float*)(ws + offB + 256);
    int*   idxArr  = (int*)(ws + offB + 1280);
    float* meanArr = (float*)(ws + offB + 881280);
    float* xmaxF   = (float*)(ws + offB + 3521280);               // M*32 f32 = 28.16MB
    uint16_t* Xb   = (uint16_t*)(ws + offB + 3521280 + 28160000); // 64*Npad bf16

    hipMemsetAsync(ws + offA, 0, zeroBytes, stream);
    hipMemsetAsync(xmaxF, 0, (size_t)M_IDS * 32 * 4, stream);
    hipMemsetAsync(d_out, 0, (size_t)V * 128 * 4, stream);

    int blocksN = (N + 255) / 256;
    float* outF = (float*)d_out;
    dim3 gridCh((Npad + 1023) / 1024, 32);

    k1_count<<<blocksN, 256, 0, stream>>>(pts, inv, cnt, sums, N);
    k2a_chunktot<<<NCHUNK, CH, 0, stream>>>(cnt, chunkTot, np);
    k2b_scan<<<1, 1024, 0, stream>>>(chunkTot, chunkBase);
    k2c_index<<<NCHUNK, CH, 0, stream>>>(cnt, sums, chunkBase, idxArr, meanArr,
                                         outF + (size_t)V * 128);
    kA_y0<<<Npad / 256, 256, 0, stream>>>(pts, w0, idxArr, inv, meanArr, Xb, N, Npad);
    kB_stats0<<<dim3(64, 32), 256, 0, stream>>>(Xb, stats, N, Npad);
    k_bnfin<<<1, 32, 0, stream>>>(stats, np, g0, b0, sb0, 32);
    kD_apply0<<<gridCh, 256, 0, stream>>>(Xb, inv, sb0, xmaxF, N, Npad);
    kE_upper<<<gridCh, 256, 0, stream>>>(Xb, inv, xmaxF, N, Npad);
    kF_gstats<<<2048, 256, 0, stream>>>(Xb, w1, stats + 64, Npad, ntiles);
    k_bnfin<<<1, 128, 0, stream>>>(stats + 64, np, g1, b1, sb1, 128);
    kH_gout<<<4096, 256, 0, stream>>>(Xb, w1, inv, sb1, (unsigned int*)d_out,
                                      N, Npad, ntiles);
}

// Round 4
// 1427.711 us; speedup vs baseline: 8.4767x; 2.6320x over previous
//
#include <hip/hip_runtime.h>
#include <cstdint>
#include <cstddef>

// ConvVFE: voxelize -> per-voxel mean -> MLP(10->32)+BN+ReLU -> voxel max
// -> concat -> MLP(64->128)+BN+ReLU -> voxel max ; plus voxel coords.
//
// R4: round-3 counters showed kH_gout = 1.9ms at VALUBusy 7% with 2.3GB
// HBM traffic -> per-point scatter atomicMax dominated. This version sorts
// points by voxel (dense CSR from the scan we already had), so every
// segment reduction is a contiguous gather with plain stores:
//   k1 histogram -> k2 scans (occ + cnt) -> k3 order-scatter -> k4 means
//   -> k5 y0 (sorted, channel-major bf16, 32 rows) -> k6 bn0 stats
//   -> k7 bn0 apply -> k8 xmax0 (V x 32, gather, no atomics)
//   -> kA GEMM stats (upper 32 rows staged from xmaxV) -> bnfin
//   -> per chunk: kB GEMM apply -> y1 bf16 ; kC voxel-major segment max
//      (plain coalesced stores; atomics only for chunk-straddling voxels).
// y1 chunk size adapts to ws_size.

constexpr int M_IDS  = 220000;
constexpr int CH     = 256;
constexpr int NCHUNK = (M_IDS + CH - 1) / CH;   // 860

__device__ __forceinline__ uint16_t f2b(float f) {
    uint32_t u = __float_as_uint(f);
    u += 0x7fffu + ((u >> 16) & 1u);
    return (uint16_t)(u >> 16);
}
__device__ __forceinline__ float b2f(uint16_t h) {
    return __uint_as_float(((uint32_t)h) << 16);
}

// ---------------------------------------------------------------- k1: merge id + histogram
__global__ void k1_count(const float* __restrict__ pts, int* __restrict__ inv,
                         int* __restrict__ cnt, int N)
{
    int i = blockIdx.x * blockDim.x + threadIdx.x;
    if (i >= N) return;
    const float* p = pts + (size_t)i * 5;
    float b = p[0], x = p[1], y = p[2], z = p[3];
    // IEEE fp32 division to bit-match numpy's floor((p - pcr)/vsz)
    float fx = floorf((x - 0.0f) / 0.32f);
    float fy = floorf((y + 40.0f) / 0.32f);
    float fz = floorf((z + 3.0f) / 4.0f);
    bool ok = (fx >= 0.0f) && (fx < 220.0f) && (fy >= 0.0f) && (fy < 250.0f) &&
              (fz >= 0.0f) && (fz < 1.0f);
    if (!ok) { inv[i] = -1; return; }
    int m = (int)b * 55000 + (int)fx * 250 + (int)fy + (int)fz;
    inv[i] = m;
    atomicAdd(&cnt[m], 1);
}

// ---------------------------------------------------------------- k2: two-level scans (occupancy + counts)
__global__ void k2a_tot(const int* __restrict__ cnt, int* __restrict__ totO,
                        int* __restrict__ totC, int* __restrict__ np)
{
    __shared__ int so[CH], sc[CH];
    int t = threadIdx.x;
    int id = blockIdx.x * CH + t;
    int c = (id < M_IDS) ? cnt[id] : 0;
    so[t] = (c > 0) ? 1 : 0;
    sc[t] = c;
    __syncthreads();
    for (int s = CH / 2; s > 0; s >>= 1) {
        if (t < s) { so[t] += so[t + s]; sc[t] += sc[t + s]; }
        __syncthreads();
    }
    if (t == 0) { totO[blockIdx.x] = so[0]; totC[blockIdx.x] = sc[0]; atomicAdd(np, sc[0]); }
}

__global__ void k2b_scan(const int* __restrict__ totO, const int* __restrict__ totC,
                         int* __restrict__ baseO, int* __restrict__ baseC)
{
    __shared__ int a[1024], bb[1024];
    int t = threadIdx.x;
    int vo = (t < NCHUNK) ? totO[t] : 0;
    int vc = (t < NCHUNK) ? totC[t] : 0;
    a[t] = vo; bb[t] = vc;
    __syncthreads();
    for (int off = 1; off < 1024; off <<= 1) {
        int xa = (t >= off) ? a[t - off] : 0;
        int xb = (t >= off) ? bb[t - off] : 0;
        __syncthreads();
        a[t] += xa; bb[t] += xb;
        __syncthreads();
    }
    baseO[t] = a[t] - vo;   // exclusive
    baseC[t] = bb[t] - vc;
}

__global__ void k2c_index(const int* __restrict__ cnt, const int* __restrict__ baseO,
                          const int* __restrict__ baseC, int* __restrict__ idxArr,
                          int* __restrict__ bOff, int* __restrict__ vOff,
                          int* __restrict__ vCnt, float* __restrict__ outCoords)
{
    __shared__ int a[CH], bb[CH];
    int t = threadIdx.x;
    int id = blockIdx.x * CH + t;
    int c = (id < M_IDS) ? cnt[id] : 0;
    int occ = (c > 0) ? 1 : 0;
    a[t] = occ; bb[t] = c;
    __syncthreads();
    for (int off = 1; off < CH; off <<= 1) {
        int xa = (t >= off) ? a[t - off] : 0;
        int xb = (t >= off) ? bb[t - off] : 0;
        __syncthreads();
        a[t] += xa; bb[t] += xb;
        __syncthreads();
    }
    if (id >= M_IDS) return;
    int g  = baseO[blockIdx.x] + a[t] - occ;
    int bo = baseC[blockIdx.x] + bb[t] - c;
    idxArr[id] = g;
    bOff[id]   = bo;
    if (occ) {
        vOff[g] = bo;
        vCnt[g] = c;
        int b2 = id / 55000;
        int rm = id % 55000;
        int cx = rm / 250;
        int cy = rm % 250;
        outCoords[(size_t)g * 4 + 0] = (float)b2;
        outCoords[(size_t)g * 4 + 1] = 0.0f;
        outCoords[(size_t)g * 4 + 2] = (float)cy;
        outCoords[(size_t)g * 4 + 3] = (float)cx;
    }
}

// ---------------------------------------------------------------- k3: scatter points to sorted order
__global__ void k3_order(const int* __restrict__ inv, const int* __restrict__ bOff,
                         const int* __restrict__ idxArr, int* __restrict__ cursor,
                         int* __restrict__ ord, int* __restrict__ vS, int N)
{
    int i = blockIdx.x * blockDim.x + threadIdx.x;
    if (i >= N) return;
    int m = inv[i];
    if (m < 0) return;
    int slot = atomicAdd(&cursor[m], 1);
    int j = bOff[m] + slot;
    ord[j] = i;
    vS[j]  = idxArr[m];
}

// ---------------------------------------------------------------- k4: per-voxel xyz mean (gather)
__global__ void k4_mean(const float* __restrict__ pts, const int* __restrict__ ord,
                        const int* __restrict__ vOff, const int* __restrict__ vCnt,
                        float* __restrict__ meanArr, int V)
{
    int g = blockIdx.x * blockDim.x + threadIdx.x;
    if (g >= V) return;
    int off = vOff[g], c = vCnt[g];
    float sx = 0.0f, sy = 0.0f, sz = 0.0f;
    for (int p = 0; p < c; p++) {
        const float* q = pts + (size_t)ord[off + p] * 5;
        sx += q[1]; sy += q[2]; sz += q[3];
    }
    float fc = (float)c;
    meanArr[(size_t)g * 3 + 0] = sx / fc;
    meanArr[(size_t)g * 3 + 1] = sy / fc;
    meanArr[(size_t)g * 3 + 2] = sz / fc;
}

// ---------------------------------------------------------------- k5: y0 = feats @ w0, sorted channel-major bf16
__global__ __launch_bounds__(256)
void k5_y0(const float* __restrict__ pts, const float* __restrict__ w0,
           const int* __restrict__ ord, const int* __restrict__ vS,
           const float* __restrict__ meanArr, uint16_t* __restrict__ Xb, int Npad)
{
    int j = blockIdx.x * 256 + threadIdx.x;   // grid = Npad/256 exactly
    float y0[32];
#pragma unroll
    for (int c = 0; c < 32; c++) y0[c] = 0.0f;
    int v = vS[j];
    if (v >= 0) {
        int i = ord[j];
        const float* p = pts + (size_t)i * 5;
        float x = p[1], y = p[2], z = p[3], it = p[4];
        float fx = floorf((x - 0.0f) / 0.32f);
        float fy = floorf((y + 40.0f) / 0.32f);
        float f[10];
        f[0] = x; f[1] = y; f[2] = z; f[3] = it;
        f[4] = x - meanArr[(size_t)v * 3 + 0];
        f[5] = y - meanArr[(size_t)v * 3 + 1];
        f[6] = z - meanArr[(size_t)v * 3 + 2];
        f[7] = x - (fx * 0.32f + 0.16f);
        f[8] = y - (fy * 0.32f - 39.84f);
        f[9] = z + 1.0f;
#pragma unroll
        for (int d = 0; d < 10; d++) {
            float fd = f[d];
#pragma unroll
            for (int c = 0; c < 32; c++) y0[c] += fd * w0[d * 32 + c];
        }
    }
#pragma unroll
    for (int c = 0; c < 32; c++) Xb[(size_t)c * Npad + j] = f2b(y0[c]);
}

// ---------------------------------------------------------------- k6: BN0 stats (row reduction)
__global__ __launch_bounds__(256, 4)
void k6_stats0(const uint16_t* __restrict__ Xb, float* __restrict__ stats0, int Npad)
{
    int c = blockIdx.y;
    const uint16_t* row = Xb + (size_t)c * Npad;
    float s = 0.0f, q = 0.0f;
    for (int i4 = (blockIdx.x * 256 + threadIdx.x) * 4; i4 < Npad;
         i4 += gridDim.x * 1024) {
        ushort4 u = *(const ushort4*)(row + i4);
        float a0 = b2f(u.x), a1 = b2f(u.y), a2 = b2f(u.z), a3 = b2f(u.w);
        s += (a0 + a1) + (a2 + a3);
        q += (a0 * a0 + a1 * a1) + (a2 * a2 + a3 * a3);
    }
#pragma unroll
    for (int m = 1; m < 64; m <<= 1) { s += __shfl_xor(s, m); q += __shfl_xor(q, m); }
    if ((threadIdx.x & 63) == 0) {
        atomicAdd(&stats0[c], s);
        atomicAdd(&stats0[32 + c], q);
    }
}

// ---------------------------------------------------------------- BN finalize
__global__ void k_bnfin(const float* __restrict__ stats, const int* __restrict__ np,
                        const float* __restrict__ g, const float* __restrict__ b,
                        float* __restrict__ sb, int C)
{
    int c = blockIdx.x * blockDim.x + threadIdx.x;
    if (c >= C) return;
    float n   = (float)(*np);
    float mu  = stats[c] / n;
    float var = stats[C + c] / n - mu * mu;
    float s   = g[c] / sqrtf(var + 1e-3f);
    sb[c]     = s;
    sb[C + c] = b[c] - mu * s;
}

// ---------------------------------------------------------------- k7: x0 = relu(bn0(y0)) in place
__global__ __launch_bounds__(256, 4)
void k7_apply0(uint16_t* __restrict__ Xb, const int* __restrict__ vS,
               const float* __restrict__ sb0, int Npad)
{
    int c = blockIdx.y;
    int i4 = (blockIdx.x * 256 + threadIdx.x) * 4;
    if (i4 >= Npad) return;
    uint16_t* row = Xb + (size_t)c * Npad;
    float sc = sb0[c], bc = sb0[32 + c];
    ushort4 u = *(const ushort4*)(row + i4);
    int4 vv = *(const int4*)(vS + i4);
    int vs[4] = {vv.x, vv.y, vv.z, vv.w};
    uint16_t hv[4] = {u.x, u.y, u.z, u.w};
    ushort4 o;
    uint16_t* op = (uint16_t*)&o;
#pragma unroll
    for (int j = 0; j < 4; j++) {
        float e = 0.0f;
        if (vs[j] >= 0) e = fmaxf(b2f(hv[j]) * sc + bc, 0.0f);
        op[j] = f2b(e);
    }
    *(ushort4*)(row + i4) = o;
}

// ---------------------------------------------------------------- k8: xmax0 gather (V x 32, no atomics)
__global__ void k8_xmax(const uint16_t* __restrict__ Xb, const int* __restrict__ vOff,
                        const int* __restrict__ vCnt, float* __restrict__ xmaxV,
                        int Npad, int V)
{
    int t = threadIdx.x;
    int g = blockIdx.x * 8 + (t >> 5);
    if (g >= V) return;
    int c = t & 31;
    int off = vOff[g], n = vCnt[g];
    const uint16_t* row = Xb + (size_t)c * Npad + off;
    float m = 0.0f;                      // relu >= 0
    for (int p = 0; p < n; p++) m = fmaxf(m, b2f(row[p]));
    xmaxV[(size_t)g * 32 + c] = m;
}

// ---------------------------------------------------------------- GEMM tile staging (lower from Xb, upper from xmaxV)
__device__ __forceinline__ void stage_x1(const uint16_t* __restrict__ Xb, int Npad,
                                         const int* __restrict__ vS,
                                         const float* __restrict__ xmaxV,
                                         int tb, float* x1s, int t)
{
    int k  = t >> 2;            // 0..63
    int cs = (t & 3) * 16;      // 16 columns
    float* dst = x1s + k * 64 + cs;
    if (k < 32) {
        const uint16_t* src = Xb + (size_t)k * Npad + tb + cs;
        uint4 u0 = *(const uint4*)(src);
        uint4 u1 = *(const uint4*)(src + 8);
        dst[0]  = __uint_as_float(u0.x << 16); dst[1]  = __uint_as_float(u0.x & 0xffff0000u);
        dst[2]  = __uint_as_float(u0.y << 16); dst[3]  = __uint_as_float(u0.y & 0xffff0000u);
        dst[4]  = __uint_as_float(u0.z << 16); dst[5]  = __uint_as_float(u0.z & 0xffff0000u);
        dst[6]  = __uint_as_float(u0.w << 16); dst[7]  = __uint_as_float(u0.w & 0xffff0000u);
        dst[8]  = __uint_as_float(u1.x << 16); dst[9]  = __uint_as_float(u1.x & 0xffff0000u);
        dst[10] = __uint_as_float(u1.y << 16); dst[11] = __uint_as_float(u1.y & 0xffff0000u);
        dst[12] = __uint_as_float(u1.z << 16); dst[13] = __uint_as_float(u1.z & 0xffff0000u);
        dst[14] = __uint_as_float(u1.w << 16); dst[15] = __uint_as_float(u1.w & 0xffff0000u);
    } else {
        int c = k - 32;
        const int* vp = vS + tb + cs;
#pragma unroll
        for (int j = 0; j < 16; j++) {
            int v = vp[j];
            dst[j] = (v >= 0) ? xmaxV[(size_t)v * 32 + c] : 0.0f;
        }
    }
}

// ---------------------------------------------------------------- kA: GEMM stats pass
__global__ __launch_bounds__(256, 2)
void kA_gstats(const uint16_t* __restrict__ Xb, const float* __restrict__ w1,
               const int* __restrict__ vS, const float* __restrict__ xmaxV,
               float* __restrict__ stats1, int Npad, int ntiles)
{
    __shared__ float w1s[64 * 128];
    __shared__ float x1s[64 * 64];
    int t = threadIdx.x;
    const float4* w1v = (const float4*)w1;
    float4* w1sv = (float4*)w1s;
    for (int j = t; j < 2048; j += 256) w1sv[j] = w1v[j];
    int p0 = (t & 15) * 4, c0 = (t >> 4) * 8;
    float s[8], q[8];
#pragma unroll
    for (int c = 0; c < 8; c++) { s[c] = 0.0f; q[c] = 0.0f; }
    for (int tile = blockIdx.x; tile < ntiles; tile += gridDim.x) {
        __syncthreads();
        stage_x1(Xb, Npad, vS, xmaxV, tile * 64, x1s, t);
        __syncthreads();
        float acc[4][8];
#pragma unroll
        for (int p = 0; p < 4; p++)
#pragma unroll
            for (int c = 0; c < 8; c++) acc[p][c] = 0.0f;
#pragma unroll 8
        for (int k = 0; k < 64; k++) {
            float4 av = *(const float4*)&x1s[k * 64 + p0];
            float4 b0 = *(const float4*)&w1s[k * 128 + c0];
            float4 b1 = *(const float4*)&w1s[k * 128 + c0 + 4];
            float a[4] = {av.x, av.y, av.z, av.w};
            float b[8] = {b0.x, b0.y, b0.z, b0.w, b1.x, b1.y, b1.z, b1.w};
#pragma unroll
            for (int p = 0; p < 4; p++)
#pragma unroll
                for (int c = 0; c < 8; c++) acc[p][c] += a[p] * b[c];
        }
#pragma unroll
        for (int c = 0; c < 8; c++) {
            float ls = 0.0f, lq = 0.0f;
#pragma unroll
            for (int p = 0; p < 4; p++) { ls += acc[p][c]; lq += acc[p][c] * acc[p][c]; }
            s[c] += ls; q[c] += lq;
        }
    }
#pragma unroll
    for (int c = 0; c < 8; c++) {
#pragma unroll
        for (int m = 1; m < 16; m <<= 1) {
            s[c] += __shfl_xor(s[c], m);
            q[c] += __shfl_xor(q[c], m);
        }
    }
    if ((t & 15) == 0) {
#pragma unroll
        for (int c = 0; c < 8; c++) {
            atomicAdd(&stats1[c0 + c],       s[c]);
            atomicAdd(&stats1[128 + c0 + c], q[c]);
        }
    }
}

// ---------------------------------------------------------------- kB: GEMM apply pass -> y1 (bf16, point-major)
__global__ __launch_bounds__(256, 2)
void kB_gemm2(const uint16_t* __restrict__ Xb, const float* __restrict__ w1,
              const int* __restrict__ vS, const float* __restrict__ xmaxV,
              const float* __restrict__ sb1, uint16_t* __restrict__ y1h,
              int Npad, int t0, int t1, int j0)
{
    __shared__ float w1s[64 * 128];
    __shared__ float x1s[64 * 64];
    int t = threadIdx.x;
    const float4* w1v = (const float4*)w1;
    float4* w1sv = (float4*)w1s;
    for (int j = t; j < 2048; j += 256) w1sv[j] = w1v[j];
    int p0 = (t & 15) * 4, c0 = (t >> 4) * 8;
    float sc[8], bc[8];
#pragma unroll
    for (int c = 0; c < 8; c++) { sc[c] = sb1[c0 + c]; bc[c] = sb1[128 + c0 + c]; }
    for (int tile = t0 + blockIdx.x; tile < t1; tile += gridDim.x) {
        __syncthreads();
        stage_x1(Xb, Npad, vS, xmaxV, tile * 64, x1s, t);
        __syncthreads();
        float acc[4][8];
#pragma unroll
        for (int p = 0; p < 4; p++)
#pragma unroll
            for (int c = 0; c < 8; c++) acc[p][c] = 0.0f;
#pragma unroll 8
        for (int k = 0; k < 64; k++) {
            float4 av = *(const float4*)&x1s[k * 64 + p0];
            float4 b0 = *(const float4*)&w1s[k * 128 + c0];
            float4 b1 = *(const float4*)&w1s[k * 128 + c0 + 4];
            float a[4] = {av.x, av.y, av.z, av.w};
            float b[8] = {b0.x, b0.y, b0.z, b0.w, b1.x, b1.y, b1.z, b1.w};
#pragma unroll
            for (int p = 0; p < 4; p++)
#pragma unroll
                for (int c = 0; c < 8; c++) acc[p][c] += a[p] * b[c];
        }
        int tb = tile * 64;
#pragma unroll
        for (int p = 0; p < 4; p++) {
            int col = tb + p0 + p;
            uint32_t w[4];
#pragma unroll
            for (int c2 = 0; c2 < 4; c2++) {
                float e0 = fmaxf(acc[p][2 * c2]     * sc[2 * c2]     + bc[2 * c2],     0.0f);
                float e1 = fmaxf(acc[p][2 * c2 + 1] * sc[2 * c2 + 1] + bc[2 * c2 + 1], 0.0f);
                w[c2] = (uint32_t)f2b(e0) | ((uint32_t)f2b(e1) << 16);
            }
            *(uint4*)(y1h + (size_t)(col - j0) * 128 + c0) = make_uint4(w[0], w[1], w[2], w[3]);
        }
    }
}

// ---------------------------------------------------------------- kC: voxel-major segment max of y1
__global__ void kC_outmax(const uint16_t* __restrict__ y1h, const int* __restrict__ vOff,
                          const int* __restrict__ vCnt, unsigned int* __restrict__ out,
                          int V, int j0, int j1)
{
    int t = threadIdx.x;
    int g = blockIdx.x * 2 + (t >> 7);
    if (g >= V) return;
    int c = t & 127;
    int off = vOff[g], end = off + vCnt[g];
    int a = off > j0 ? off : j0;
    int e = end < j1 ? end : j1;
    if (a >= e) return;
    float m = 0.0f;                      // relu >= 0
    for (int p = a; p < e; p++) m = fmaxf(m, b2f(y1h[(size_t)(p - j0) * 128 + c]));
    size_t oa = (size_t)g * 128 + c;
    if (off >= j0 && end <= j1) out[oa] = __float_as_uint(m);   // interior: single writer
    else if (m > 0.0f) atomicMax(&out[oa], __float_as_uint(m)); // chunk-straddling voxel
}

// ---------------------------------------------------------------- launch
extern "C" void kernel_launch(void* const* d_in, const int* in_sizes, int n_in,
                              void* d_out, int out_size, void* d_ws, size_t ws_size,
                              hipStream_t stream)
{
    const float* pts = (const float*)d_in[0];
    const float* w0  = (const float*)d_in[1];
    const float* g0  = (const float*)d_in[2];
    const float* b0  = (const float*)d_in[3];
    const float* w1  = (const float*)d_in[4];
    const float* g1  = (const float*)d_in[5];
    const float* b1  = (const float*)d_in[6];

    int N    = in_sizes[0] / 5;
    int V    = out_size / 132;
    int Npad = (N + 255) & ~255;
    int ntiles = Npad / 64;

    char* ws = (char*)d_ws;
    size_t off = 0;
    auto alloc = [&](size_t bytes) { size_t r = off; off = (off + bytes + 255) & ~(size_t)255; return r; };

    int*   inv     = (int*)(ws + alloc((size_t)N * 4));
    int*   ord     = (int*)(ws + alloc((size_t)Npad * 4));
    int*   vS      = (int*)(ws + alloc((size_t)Npad * 4));
    size_t zOff    = off;                                   // zero block start
    int*   cnt     = (int*)(ws + alloc((size_t)M_IDS * 4));
    int*   cursor  = (int*)(ws + alloc((size_t)M_IDS * 4));
    float* stats   = (float*)(ws + alloc(320 * 4));         // bn0: 64 | bn1: 256
    int*   np      = (int*)(ws + alloc(4));
    size_t zBytes  = off - zOff;
    int*   bOff    = (int*)(ws + alloc((size_t)M_IDS * 4));
    int*   idxArr  = (int*)(ws + alloc((size_t)M_IDS * 4));
    int*   vOff    = (int*)(ws + alloc((size_t)M_IDS * 4));
    int*   vCnt    = (int*)(ws + alloc((size_t)M_IDS * 4));
    int*   totO    = (int*)(ws + alloc(1024 * 4));
    int*   totC    = (int*)(ws + alloc(1024 * 4));
    int*   baseO   = (int*)(ws + alloc(1024 * 4));
    int*   baseC   = (int*)(ws + alloc(1024 * 4));
    float* sb0     = (float*)(ws + alloc(64 * 4));
    float* sb1     = (float*)(ws + alloc(256 * 4));
    float* meanArr = (float*)(ws + alloc((size_t)V * 12));
    float* xmaxV   = (float*)(ws + alloc((size_t)V * 128));
    uint16_t* Xb   = (uint16_t*)(ws + alloc((size_t)32 * Npad * 2));
    uint16_t* y1h  = (uint16_t*)(ws + off);

    // y1 chunking sized from remaining workspace (256 B per point row)
    size_t avail = (ws_size > off) ? (ws_size - off) : 0;
    size_t maxPts = (avail / 256) & ~(size_t)63;
    int chunkPts = (maxPts >= (size_t)Npad) ? Npad
                 : (maxPts >= 64 ? (int)maxPts : 64);
    int nch = (Npad + chunkPts - 1) / chunkPts;

    hipMemsetAsync(ws + zOff, 0, zBytes, stream);
    hipMemsetAsync(vS, 0xFF, (size_t)Npad * 4, stream);
    hipMemsetAsync(d_out, 0, (size_t)V * 128 * 4, stream);

    int blocksN = (N + 255) / 256;
    float* outF = (float*)d_out;

    k1_count<<<blocksN, 256, 0, stream>>>(pts, inv, cnt, N);
    k2a_tot<<<NCHUNK, CH, 0, stream>>>(cnt, totO, totC, np);
    k2b_scan<<<1, 1024, 0, stream>>>(totO, totC, baseO, baseC);
    k2c_index<<<NCHUNK, CH, 0, stream>>>(cnt, baseO, baseC, idxArr, bOff, vOff, vCnt,
                                         outF + (size_t)V * 128);
    k3_order<<<blocksN, 256, 0, stream>>>(inv, bOff, idxArr, cursor, ord, vS, N);
    k4_mean<<<(V + 255) / 256, 256, 0, stream>>>(pts, ord, vOff, vCnt, meanArr, V);
    k5_y0<<<Npad / 256, 256, 0, stream>>>(pts, w0, ord, vS, meanArr, Xb, Npad);
    k6_stats0<<<dim3(64, 32), 256, 0, stream>>>(Xb, stats, Npad);
    k_bnfin<<<1, 32, 0, stream>>>(stats, np, g0, b0, sb0, 32);
    k7_apply0<<<dim3((Npad + 1023) / 1024, 32), 256, 0, stream>>>(Xb, vS, sb0, Npad);
    k8_xmax<<<(V + 7) / 8, 256, 0, stream>>>(Xb, vOff, vCnt, xmaxV, Npad, V);
    kA_gstats<<<2048, 256, 0, stream>>>(Xb, w1, vS, xmaxV, stats + 64, Npad, ntiles);
    k_bnfin<<<1, 128, 0, stream>>>(stats + 64, np, g1, b1, sb1, 128);

    for (int ch = 0; ch < nch; ch++) {
        int j0 = ch * chunkPts;
        int j1 = (j0 + chunkPts < Npad) ? (j0 + chunkPts) : Npad;
        int t0 = j0 / 64, t1 = j1 / 64;
        int nb = t1 - t0; if (nb > 2048) nb = 2048;
        kB_gemm2<<<nb, 256, 0, stream>>>(Xb, w1, vS, xmaxV, sb1, y1h, Npad, t0, t1, j0);
        kC_outmax<<<(V + 1) / 2, 256, 0, stream>>>(y1h, vOff, vCnt,
                                                   (unsigned int*)d_out, V, j0, j1);
    }
}